// Round 1
// 270.283 us; speedup vs baseline: 1.0156x; 1.0156x over previous
//
#include <hip/hip_runtime.h>
#include <math.h>

// MSTAGNN: N nodes, E edges (propagation), FE full edges (regression head).
// HC=64, HEADS=4, HEADC=DV=16, KHOP=3, NUM_T=128.
// R8 design: wave-per-node hop (64 lanes/node, no LDS, no barriers), 8-deep
// edge pipeline with readlane SGPR bases; hop0 rebuilt as Kf/V outer-product
// gather (no M0 materialization); edge head factored into per-node P1/P2.

#define HC 64
#define HEADS 4
#define KHOP 3
#define NUM_T 128
#define MSZ 1024    // bytes per node M row (fp8)
#define SLOTS 64    // padded CSR slots per node
#define CST 1e-5f

typedef float f32x2 __attribute__((ext_vector_type(2)));

// ---- bf16 helpers (storage-only precision; accumulate in fp32) ----
__device__ __forceinline__ float bf2f(unsigned short s) { return __uint_as_float(((unsigned int)s) << 16); }
__device__ __forceinline__ float bfu_lo(unsigned int u) { return __uint_as_float(u << 16); }
__device__ __forceinline__ float bfu_hi(unsigned int u) { return __uint_as_float(u & 0xffff0000u); }
__device__ __forceinline__ unsigned short f2bf(float f) {
    unsigned int u = __float_as_uint(f);
    u = (u + 0x7fffu + ((u >> 16) & 1u)) >> 16;   // RTNE
    return (unsigned short)u;
}
// ---- fp8 e4m3 via HW pack/unpack (gfx950 OCP) ----
__device__ __forceinline__ unsigned int pack4fp8(float a, float b, float c, float d) {
    int r = __builtin_amdgcn_cvt_pk_fp8_f32(a, b, 0, false);       // bytes 0,1
    r = __builtin_amdgcn_cvt_pk_fp8_f32(c, d, r, true);            // bytes 2,3
    return (unsigned int)r;
}

// ---------------- padded-CSR fill: cnt[c]++ ; csr[c*64+k] = row ----------------
__global__ void k_fill(const int* __restrict__ row, const int* __restrict__ col,
                       int* __restrict__ cnt, int* __restrict__ csr, int E) {
    int e = blockIdx.x * 256 + threadIdx.x;
    if (e >= E) return;
    int c = col[e];
    int r = row[e];
    int k = atomicAdd(&cnt[c], 1);
    if (k < SLOTS) csr[c * SLOTS + k] = r;
}

// ------- misc: temb table (blocks 0..31) + gamma (block 0) + inv_deg (blocks 32+) -------
__global__ __launch_bounds__(256) void k_misc(
    const float* __restrict__ Wt1, const float* __restrict__ bt1,
    const float* __restrict__ Wt2, const float* __restrict__ bt2,
    const float* __restrict__ hopwise, const float* __restrict__ headwise,
    const int* __restrict__ cnt,
    float* __restrict__ gamma, float* __restrict__ table,
    float* __restrict__ inv_deg, int n) {
    if (blockIdx.x >= 32) {
        int i = (blockIdx.x - 32) * 256 + threadIdx.x;
        if (i < n) {
            int d = cnt[i];
            inv_deg[i] = (d > 0) ? 1.0f / (float)min(d, SLOTS) : 0.0f;
        }
        return;
    }
    if (blockIdx.x == 0 && threadIdx.x == 0) {
        for (int k = 0; k < KHOP; k++) {
            float m = -1e30f;
            for (int h2 = 0; h2 < HEADS; h2++) m = fmaxf(m, headwise[h2 * KHOP + k]);
            float ex[HEADS]; float s = 0.f;
            for (int h2 = 0; h2 < HEADS; h2++) { ex[h2] = expf(headwise[h2 * KHOP + k] - m); s += ex[h2]; }
            for (int h2 = 0; h2 < HEADS; h2++) gamma[k * HEADS + h2] = hopwise[k + 1] * ex[h2] / s;
        }
    }
    int slot = threadIdx.x >> 6;
    int j = threadIdx.x & 63;
    int tval = blockIdx.x * 4 + slot;                  // 0..127
    __shared__ float emb_s[4][64];
    __shared__ float z1_s[4][256];
    {
        float t = (float)tval * 31.25f;                // 4000/128
        float e;
        if (j < 32) e = sinf(t * expf(-0.2971077539347156f * (float)j));
        else        e = cosf(t * expf(-0.2971077539347156f * (float)(j - 32)));
        emb_s[slot][j] = e;
    }
    __syncthreads();
    {
        #pragma unroll
        for (int k = 0; k < 4; k++) {
            int o = j + 64 * k;
            float acc = bt1[o];
            for (int i = 0; i < 64; i++) acc += emb_s[slot][i] * Wt1[i * 256 + o];
            z1_s[slot][o] = acc / (1.f + expf(-acc));  // silu
        }
    }
    __syncthreads();
    {
        float acc = bt2[j];
        for (int i = 0; i < 256; i++) acc += z1_s[slot][i] * Wt2[i * 64 + j];
        table[tval * 64 + j] = acc;
    }
}

// ---- fused node kernel: h -> QKV -> Q, hidden, pre-scaled Kf0'(bf16), V(bf16) ----
// (no M0 materialization: hop0 consumes Kf'/V directly as an outer product)
__global__ __launch_bounds__(256) void k_node(
    const float* __restrict__ x, const int* __restrict__ time_steps,
    const float* __restrict__ temb, const float* __restrict__ Wi,
    const float* __restrict__ bi,
    const float* __restrict__ WQ, const float* __restrict__ bQ,
    const float* __restrict__ WK, const float* __restrict__ bK,
    const float* __restrict__ WV, const float* __restrict__ bV,
    const float* __restrict__ hopwise, const float* __restrict__ inv_deg,
    float* __restrict__ Q, unsigned short* __restrict__ Kf0,
    unsigned short* __restrict__ Vbuf, float* __restrict__ hidden, int n) {
    __shared__ float xs[16][128];                      // 8 KB
    __shared__ float hs[16][64];                       // 4 KB
    int j = threadIdx.x & 63;
    int slot = threadIdx.x >> 6;                       // wave id
    int nbase = blockIdx.x * 16;
    int nvalid = min(16, n - nbase);
    const float4* xg = (const float4*)(x + (size_t)nbase * 128);
    float4* xs4 = (float4*)&xs[0][0];
    for (int idx = threadIdx.x; idx < nvalid * 32; idx += 256) xs4[idx] = xg[idx];
    __syncthreads();
    int nl = slot * 4;
    {
        float acc[4];
        #pragma unroll
        for (int k = 0; k < 4; k++) acc[k] = 0.f;
        #pragma unroll 8
        for (int i = 0; i < 128; i++) {
            float w = Wi[i * 64 + j];
            #pragma unroll
            for (int k = 0; k < 4; k++) acc[k] += xs[nl + k][i] * w;
        }
        float bj = bi[j];
        #pragma unroll
        for (int k = 0; k < 4; k++) {
            int node = nbase + nl + k;
            float te = (node < n) ? temb[time_steps[node] * 64 + j] : 0.f;
            hs[nl + k][j] = fmaxf(acc[k] + bj + te, 0.f);
        }
    }
    __syncthreads();
    float aq[4], ak[4], av[4];
    #pragma unroll
    for (int k = 0; k < 4; k++) { aq[k] = bQ[j]; ak[k] = bK[j]; av[k] = bV[j]; }
    #pragma unroll 4
    for (int i = 0; i < 64; i++) {
        float wq = WQ[i * 64 + j], wk = WK[i * 64 + j], wv = WV[i * 64 + j];
        #pragma unroll
        for (int k = 0; k < 4; k++) {
            float hv = hs[nl + k][i];
            aq[k] += hv * wq; ak[k] += hv * wk; av[k] += hv * wv;
        }
    }
    float h0 = hopwise[0];
    #pragma unroll
    for (int k = 0; k < 4; k++) {
        int node = nbase + nl + k;
        if (node < n) {
            float q  = 1.f + ((aq[k] > 0.f) ? aq[k] : (expf(aq[k]) - 1.f));
            float kf = 1.f + ((ak[k] > 0.f) ? ak[k] : (expf(ak[k]) - 1.f));
            float inv = inv_deg[node];
            Q[(size_t)node * 64 + j] = q;
            Kf0[(size_t)node * 64 + j] = f2bf(kf * inv);       // pre-scaled Kf'
            Vbuf[(size_t)node * 64 + j] = f2bf(av[k]);
            hidden[(size_t)node * 64 + j] = av[k] * h0;
        }
    }
}

// ---- hop: wave-per-node (64 lanes), no LDS, no barriers.
// MODE 0: outer-product gather from Kf'(bf16) + V(bf16)  [hop 0]
// MODE 1: dense gather from M(fp8) rows                  [hops 1,2]
// lane <-> element mapping: e = lane*16 + j ; h = lane>>4, i = lane&15, j=0..15
template<int MODE>
__global__ __launch_bounds__(256) void k_hop(
    const unsigned char* __restrict__ Mold, const unsigned short* __restrict__ Kfold,
    const unsigned short* __restrict__ Vbuf,
    const int* __restrict__ cnt, const int* __restrict__ csr,
    const float* __restrict__ inv_deg, const float* __restrict__ Q,
    const float* __restrict__ gamma,
    unsigned char* __restrict__ Mnew, unsigned short* __restrict__ Kfnew,
    float* __restrict__ hidden, int hop, int write_out,
    const float* __restrict__ Wo, const float* __restrict__ bo,
    const float* __restrict__ Wf1, float* __restrict__ out16,
    float* __restrict__ Pbuf, int n) {
    constexpr int DEPTH = (MODE == 0) ? 4 : 8;
    int lane = threadIdx.x & 63;
    int node = blockIdx.x * 4 + (threadIdx.x >> 6);
    if (node >= n) return;
    int grp = lane >> 4;                               // head h
    int deg = min(cnt[node], SLOTS);
    int degU = __builtin_amdgcn_readfirstlane(deg);
    int sidx = csr[(size_t)node * SLOTS + lane];       // all 64 slots, one load
    float qv = Q[(size_t)node * 64 + lane];
    float acc[16];
    #pragma unroll
    for (int t = 0; t < 16; t++) acc[t] = 0.f;
    float kacc = 0.f;

    for (int base = 0; base < degU; base += DEPTH) {
        unsigned short kraw[DEPTH];
        uint4 m0[DEPTH], m1[DEPTH];
        #pragma unroll
        for (int t = 0; t < DEPTH; t++) {
            int d = base + t;
            int dc = (d < degU) ? d : (degU - 1);
            int s = __builtin_amdgcn_readlane(sidx, dc);   // SGPR base per edge
            kraw[t] = Kfold[(size_t)s * 64 + lane];
            if constexpr (MODE == 0) {
                const uint4* vp = (const uint4*)((const unsigned char*)Vbuf + (size_t)s * 128 + grp * 32);
                m0[t] = vp[0];                             // V[h, 0..7]  (bf16)
                m1[t] = vp[1];                             // V[h, 8..15] (bf16)
            } else {
                m0[t] = *(const uint4*)(Mold + (size_t)s * MSZ + lane * 16);
            }
        }
        #pragma unroll
        for (int t = 0; t < DEPTH; t++) {
            float wt = (base + t < degU) ? 1.f : 0.f;      // tail lanes masked
            float kf = bf2f(kraw[t]);
            kacc = fmaf(wt, kf, kacc);
            if constexpr (MODE == 0) {
                float kw = kf * wt;                        // M contribution = Kf' * V
                acc[0]  = fmaf(kw, bfu_lo(m0[t].x), acc[0]);
                acc[1]  = fmaf(kw, bfu_hi(m0[t].x), acc[1]);
                acc[2]  = fmaf(kw, bfu_lo(m0[t].y), acc[2]);
                acc[3]  = fmaf(kw, bfu_hi(m0[t].y), acc[3]);
                acc[4]  = fmaf(kw, bfu_lo(m0[t].z), acc[4]);
                acc[5]  = fmaf(kw, bfu_hi(m0[t].z), acc[5]);
                acc[6]  = fmaf(kw, bfu_lo(m0[t].w), acc[6]);
                acc[7]  = fmaf(kw, bfu_hi(m0[t].w), acc[7]);
                acc[8]  = fmaf(kw, bfu_lo(m1[t].x), acc[8]);
                acc[9]  = fmaf(kw, bfu_hi(m1[t].x), acc[9]);
                acc[10] = fmaf(kw, bfu_lo(m1[t].y), acc[10]);
                acc[11] = fmaf(kw, bfu_hi(m1[t].y), acc[11]);
                acc[12] = fmaf(kw, bfu_lo(m1[t].z), acc[12]);
                acc[13] = fmaf(kw, bfu_hi(m1[t].z), acc[13]);
                acc[14] = fmaf(kw, bfu_lo(m1[t].w), acc[14]);
                acc[15] = fmaf(kw, bfu_hi(m1[t].w), acc[15]);
            } else {
                f32x2 p;
                p = __builtin_amdgcn_cvt_pk_f32_fp8((int)m0[t].x, false); acc[0]  = fmaf(wt, p.x, acc[0]);  acc[1]  = fmaf(wt, p.y, acc[1]);
                p = __builtin_amdgcn_cvt_pk_f32_fp8((int)m0[t].x, true);  acc[2]  = fmaf(wt, p.x, acc[2]);  acc[3]  = fmaf(wt, p.y, acc[3]);
                p = __builtin_amdgcn_cvt_pk_f32_fp8((int)m0[t].y, false); acc[4]  = fmaf(wt, p.x, acc[4]);  acc[5]  = fmaf(wt, p.y, acc[5]);
                p = __builtin_amdgcn_cvt_pk_f32_fp8((int)m0[t].y, true);  acc[6]  = fmaf(wt, p.x, acc[6]);  acc[7]  = fmaf(wt, p.y, acc[7]);
                p = __builtin_amdgcn_cvt_pk_f32_fp8((int)m0[t].z, false); acc[8]  = fmaf(wt, p.x, acc[8]);  acc[9]  = fmaf(wt, p.y, acc[9]);
                p = __builtin_amdgcn_cvt_pk_f32_fp8((int)m0[t].z, true);  acc[10] = fmaf(wt, p.x, acc[10]); acc[11] = fmaf(wt, p.y, acc[11]);
                p = __builtin_amdgcn_cvt_pk_f32_fp8((int)m0[t].w, false); acc[12] = fmaf(wt, p.x, acc[12]); acc[13] = fmaf(wt, p.y, acc[13]);
                p = __builtin_amdgcn_cvt_pk_f32_fp8((int)m0[t].w, true);  acc[14] = fmaf(wt, p.x, acc[14]); acc[15] = fmaf(wt, p.y, acc[15]);
            }
        }
    }

    if (write_out) {
        float inv = inv_deg[node];
        uint4 st;
        st.x = pack4fp8(acc[0] * inv,  acc[1] * inv,  acc[2] * inv,  acc[3] * inv);
        st.y = pack4fp8(acc[4] * inv,  acc[5] * inv,  acc[6] * inv,  acc[7] * inv);
        st.z = pack4fp8(acc[8] * inv,  acc[9] * inv,  acc[10] * inv, acc[11] * inv);
        st.w = pack4fp8(acc[12] * inv, acc[13] * inv, acc[14] * inv, acc[15] * inv);
        *(uint4*)(Mnew + (size_t)node * MSZ + lane * 16) = st;
        Kfnew[(size_t)node * 64 + lane] = f2bf(kacc * inv);
    }

    // C[h] = sum_i Q[h,i]*Kf[h,i]  — 16-lane allreduce within head group
    float c = qv * kacc;
    c += __shfl_xor(c, 1); c += __shfl_xor(c, 2); c += __shfl_xor(c, 4); c += __shfl_xor(c, 8);

    // H[h,j] = sum_i Q[h,i]*M[h,i,j] — reduce-scatter over the 16 i-lanes so
    // lane (h,i) ends holding H[h, j=i] (static indices only; no scratch).
    float w0[16];
    #pragma unroll
    for (int t = 0; t < 16; t++) w0[t] = qv * acc[t];
    float w1r[8];
    #pragma unroll
    for (int t = 0; t < 8; t++) {
        float a = w0[2 * t], b = w0[2 * t + 1];
        float mine = (lane & 1) ? b : a, th = (lane & 1) ? a : b;
        w1r[t] = mine + __shfl_xor(th, 1);
    }
    float w2r[4];
    #pragma unroll
    for (int t = 0; t < 4; t++) {
        float a = w1r[2 * t], b = w1r[2 * t + 1];
        float mine = (lane & 2) ? b : a, th = (lane & 2) ? a : b;
        w2r[t] = mine + __shfl_xor(th, 2);
    }
    float w3r[2];
    #pragma unroll
    for (int t = 0; t < 2; t++) {
        float a = w2r[2 * t], b = w2r[2 * t + 1];
        float mine = (lane & 4) ? b : a, th = (lane & 4) ? a : b;
        w3r[t] = mine + __shfl_xor(th, 4);
    }
    float Hv;
    {
        float a = w3r[0], b = w3r[1];
        float mine = (lane & 8) ? b : a, th = (lane & 8) ? a : b;
        Hv = mine + __shfl_xor(th, 8);
    }

    float g = gamma[hop * HEADS + grp];
    float contrib = g * Hv / (c + CST);
    size_t hoff = (size_t)node * 64 + lane;
    if (write_out) {
        hidden[hoff] = hidden[hoff] + contrib;
    } else {
        // final hop: fused Wo projection + bo, plus per-node P1/P2 for edge head
        float hid = hidden[hoff] + contrib;
        const float4* wop = (const float4*)(Wo + lane * 16);
        float4 wo0 = wop[0], wo1 = wop[1], wo2 = wop[2], wo3 = wop[3];
        float v[16];
        v[0] = hid * wo0.x;  v[1] = hid * wo0.y;  v[2] = hid * wo0.z;  v[3] = hid * wo0.w;
        v[4] = hid * wo1.x;  v[5] = hid * wo1.y;  v[6] = hid * wo1.z;  v[7] = hid * wo1.w;
        v[8] = hid * wo2.x;  v[9] = hid * wo2.y;  v[10] = hid * wo2.z; v[11] = hid * wo2.w;
        v[12] = hid * wo3.x; v[13] = hid * wo3.y; v[14] = hid * wo3.z; v[15] = hid * wo3.w;
        #pragma unroll
        for (int m = 32; m >= 1; m >>= 1) {
            #pragma unroll
            for (int o = 0; o < 16; o++) v[o] += __shfl_xor(v[o], m);
        }
        #pragma unroll
        for (int o = 0; o < 16; o++) v[o] += bo[o];
        if (lane == 0) {
            float4* op = (float4*)(out16 + (size_t)node * 16);
            op[0] = make_float4(v[0],  v[1],  v[2],  v[3]);
            op[1] = make_float4(v[4],  v[5],  v[6],  v[7]);
            op[2] = make_float4(v[8],  v[9],  v[10], v[11]);
            op[3] = make_float4(v[12], v[13], v[14], v[15]);
        }
        if (lane < 32) {
            int o = lane & 15, half = lane >> 4;
            const float* wf = Wf1 + (size_t)(half * 16) * 16 + o;
            float p = 0.f;
            #pragma unroll
            for (int i = 0; i < 16; i++) p += v[i] * wf[i * 16];
            Pbuf[(size_t)node * 32 + lane] = p;         // [n][0:16]=P1(src), [16:32]=P2(dst)
        }
    }
}

// ---------------- edge regression head: z = P1[s] + P2[d] + b1 ----------------
__global__ __launch_bounds__(256) void k_edge(
    const int* __restrict__ src, const int* __restrict__ dst,
    const float* __restrict__ Pbuf,
    const float* __restrict__ bf1, const float* __restrict__ Wf2,
    const float* __restrict__ bf2,
    float* __restrict__ out, int fe) {
    __shared__ float b1[16];
    __shared__ float w2[16];
    __shared__ float b2s;
    int t = threadIdx.x;
    if (t < 16) { b1[t] = bf1[t]; w2[t] = Wf2[t]; }
    if (t == 0) b2s = bf2[0];
    __syncthreads();
    int e = blockIdx.x * 256 + t;
    if (e >= fe) return;
    int s = src[e], d = dst[e];
    const float4* p1 = (const float4*)(Pbuf + (size_t)s * 32);
    const float4* p2 = (const float4*)(Pbuf + (size_t)d * 32 + 16);
    float z[16];
    #pragma unroll
    for (int q = 0; q < 4; q++) {
        float4 a = p1[q]; float4 b = p2[q];
        z[q * 4 + 0] = a.x + b.x; z[q * 4 + 1] = a.y + b.y;
        z[q * 4 + 2] = a.z + b.z; z[q * 4 + 3] = a.w + b.w;
    }
    float acc = b2s;
    #pragma unroll
    for (int o = 0; o < 16; o++) {
        float zz = z[o] + b1[o];
        zz = zz / (1.f + expf(-zz));       // silu
        acc += zz * w2[o];
    }
    out[e] = acc;
}

extern "C" void kernel_launch(void* const* d_in, const int* in_sizes, int n_in,
                              void* d_out, int out_size, void* d_ws, size_t ws_size,
                              hipStream_t stream) {
    const float* x        = (const float*)d_in[0];
    const int*   eidx     = (const int*)d_in[1];
    const int*   feidx    = (const int*)d_in[2];
    const int*   tsteps   = (const int*)d_in[3];
    const float* Wi  = (const float*)d_in[4];
    const float* bi  = (const float*)d_in[5];
    const float* Wt1 = (const float*)d_in[6];
    const float* bt1 = (const float*)d_in[7];
    const float* Wt2 = (const float*)d_in[8];
    const float* bt2 = (const float*)d_in[9];
    const float* WQ  = (const float*)d_in[10];
    const float* bQ  = (const float*)d_in[11];
    const float* WK  = (const float*)d_in[12];
    const float* bK  = (const float*)d_in[13];
    const float* WV  = (const float*)d_in[14];
    const float* bV  = (const float*)d_in[15];
    const float* Wo  = (const float*)d_in[16];
    const float* bo  = (const float*)d_in[17];
    const float* hopwise  = (const float*)d_in[18];
    const float* headwise = (const float*)d_in[19];
    const float* Wf1 = (const float*)d_in[20];
    const float* bf1 = (const float*)d_in[21];
    const float* Wf2 = (const float*)d_in[22];
    const float* bf2 = (const float*)d_in[23];

    const int N  = in_sizes[3];
    const int E  = in_sizes[1] / 2;
    const int FE = in_sizes[2] / 2;
    const int* row = eidx;           // [0,:]
    const int* col = eidx + E;       // [1,:]
    const int* fsrc = feidx;
    const int* fdst = feidx + FE;

    // ---- workspace carve-up (256B aligned) ----
    char* ws = (char*)d_ws;
    size_t off = 0;
    auto alloc = [&](size_t bytes) -> char* {
        char* p = ws + off;
        off = (off + bytes + 255) & ~(size_t)255;
        return p;
    };
    float* gamma     = (float*)alloc(KHOP * HEADS * sizeof(float));
    int*   cnt       = (int*)alloc((size_t)N * 4);
    int*   csr       = (int*)alloc((size_t)N * SLOTS * 4);
    float* inv_deg   = (float*)alloc((size_t)N * 4);
    float* temb      = (float*)alloc((size_t)NUM_T * HC * 4);
    float* Qbuf      = (float*)alloc((size_t)N * HC * 4);
    unsigned short* Kf0  = (unsigned short*)alloc((size_t)N * HC * 2);
    unsigned short* Kf_a = (unsigned short*)alloc((size_t)N * HC * 2);
    unsigned short* Kf_b = (unsigned short*)alloc((size_t)N * HC * 2);
    unsigned short* Vbuf = (unsigned short*)alloc((size_t)N * HC * 2);
    float* hidden    = (float*)alloc((size_t)N * HC * 4);
    unsigned char* M_a = (unsigned char*)alloc((size_t)N * MSZ);
    unsigned char* M_b = (unsigned char*)alloc((size_t)N * MSZ);
    float* Pbuf      = (float*)alloc((size_t)N * 32 * 4);
    (void)ws_size;

    float* out_edges = (float*)d_out;            // [FE]
    float* out_hid16 = (float*)d_out + FE;       // [N,16]

    const int miscBlocks = 32 + (N + 255) / 256;
    const int hopBlocks = (N + 3) / 4;

    (void)hipMemsetAsync(cnt, 0, (size_t)N * 4, stream);
    k_fill<<<(E + 255) / 256, 256, 0, stream>>>(row, col, cnt, csr, E);
    k_misc<<<miscBlocks, 256, 0, stream>>>(Wt1, bt1, Wt2, bt2, hopwise, headwise,
                                           cnt, gamma, temb, inv_deg, N);
    k_node<<<(N + 15) / 16, 256, 0, stream>>>(x, tsteps, temb, Wi, bi,
                                              WQ, bQ, WK, bK, WV, bV, hopwise, inv_deg,
                                              Qbuf, Kf0, Vbuf, hidden, N);
    // hop 0: outer-product gather (Kf0', V) -> M_a', Kf_a'
    k_hop<0><<<hopBlocks, 256, 0, stream>>>(nullptr, Kf0, Vbuf, cnt, csr, inv_deg, Qbuf, gamma,
                                            M_a, Kf_a, hidden, 0, 1, Wo, bo, Wf1, out_hid16, Pbuf, N);
    // hop 1: dense M_a' -> M_b'
    k_hop<1><<<hopBlocks, 256, 0, stream>>>(M_a, Kf_a, nullptr, cnt, csr, inv_deg, Qbuf, gamma,
                                            M_b, Kf_b, hidden, 1, 1, Wo, bo, Wf1, out_hid16, Pbuf, N);
    // hop 2: dense gather M_b', no write, fused Wo projection + P1/P2
    k_hop<1><<<hopBlocks, 256, 0, stream>>>(M_b, Kf_b, nullptr, cnt, csr, inv_deg, Qbuf, gamma,
                                            M_a, Kf_a, hidden, 2, 0, Wo, bo, Wf1, out_hid16, Pbuf, N);
    k_edge<<<(FE + 255) / 256, 256, 0, stream>>>(fsrc, fdst, Pbuf, bf1, Wf2, bf2,
                                                 out_edges, FE);
}

// Round 2
// 253.909 us; speedup vs baseline: 1.0811x; 1.0645x over previous
//
#include <hip/hip_runtime.h>
#include <math.h>

// MSTAGNN: N nodes, E edges (propagation), FE full edges (regression head).
// HC=64, HEADS=4, HEADC=DV=16, KHOP=3, NUM_T=128.
// R9: wave-per-node hop (64 lanes/node, no LDS, no barriers), 8-deep edge
// pipeline; exact guarded tail (no duplicate clamped loads); 128-thr blocks
// (2 nodes) for fine-grain balance; hop0 = Kf/V outer-product gather;
// edge head factored into per-node P1/P2; k_misc temb parallelized 128-wide.

#define HC 64
#define HEADS 4
#define KHOP 3
#define NUM_T 128
#define MSZ 1024    // bytes per node M row (fp8)
#define SLOTS 64    // padded CSR slots per node
#define CST 1e-5f

typedef float f32x2 __attribute__((ext_vector_type(2)));

// ---- bf16 helpers (storage-only precision; accumulate in fp32) ----
__device__ __forceinline__ float bf2f(unsigned short s) { return __uint_as_float(((unsigned int)s) << 16); }
__device__ __forceinline__ float bfu_lo(unsigned int u) { return __uint_as_float(u << 16); }
__device__ __forceinline__ float bfu_hi(unsigned int u) { return __uint_as_float(u & 0xffff0000u); }
__device__ __forceinline__ unsigned short f2bf(float f) {
    unsigned int u = __float_as_uint(f);
    u = (u + 0x7fffu + ((u >> 16) & 1u)) >> 16;   // RTNE
    return (unsigned short)u;
}
// ---- fp8 e4m3 via HW pack/unpack (gfx950 OCP) ----
__device__ __forceinline__ unsigned int pack4fp8(float a, float b, float c, float d) {
    int r = __builtin_amdgcn_cvt_pk_fp8_f32(a, b, 0, false);       // bytes 0,1
    r = __builtin_amdgcn_cvt_pk_fp8_f32(c, d, r, true);            // bytes 2,3
    return (unsigned int)r;
}

// ---------------- padded-CSR fill: cnt[c]++ ; csr[c*64+k] = row ----------------
__global__ void k_fill(const int* __restrict__ row, const int* __restrict__ col,
                       int* __restrict__ cnt, int* __restrict__ csr, int E) {
    int e = blockIdx.x * 256 + threadIdx.x;
    if (e >= E) return;
    int c = col[e];
    int r = row[e];
    int k = atomicAdd(&cnt[c], 1);
    if (k < SLOTS) csr[c * SLOTS + k] = r;
}

// ------- misc: temb table (blocks 0..127, one tval each) + gamma (block 0)
//         + inv_deg (blocks 128+) -------
__global__ __launch_bounds__(256) void k_misc(
    const float* __restrict__ Wt1, const float* __restrict__ bt1,
    const float* __restrict__ Wt2, const float* __restrict__ bt2,
    const float* __restrict__ hopwise, const float* __restrict__ headwise,
    const int* __restrict__ cnt,
    float* __restrict__ gamma, float* __restrict__ table,
    float* __restrict__ inv_deg, int n) {
    if (blockIdx.x >= NUM_T) {
        int i = (blockIdx.x - NUM_T) * 256 + threadIdx.x;
        if (i < n) {
            int d = cnt[i];
            inv_deg[i] = (d > 0) ? 1.0f / (float)min(d, SLOTS) : 0.0f;
        }
        return;
    }
    if (blockIdx.x == 0 && threadIdx.x == 0) {
        for (int k = 0; k < KHOP; k++) {
            float m = -1e30f;
            for (int h2 = 0; h2 < HEADS; h2++) m = fmaxf(m, headwise[h2 * KHOP + k]);
            float ex[HEADS]; float s = 0.f;
            for (int h2 = 0; h2 < HEADS; h2++) { ex[h2] = expf(headwise[h2 * KHOP + k] - m); s += ex[h2]; }
            for (int h2 = 0; h2 < HEADS; h2++) gamma[k * HEADS + h2] = hopwise[k + 1] * ex[h2] / s;
        }
    }
    int t = threadIdx.x;
    int tval = blockIdx.x;                           // 0..127
    __shared__ float emb_s[64];
    __shared__ float z1_s[256];
    __shared__ float ps_s[4][64];
    if (t < 64) {
        float tt = (float)tval * 31.25f;             // 4000/128
        float e;
        if (t < 32) e = sinf(tt * expf(-0.2971077539347156f * (float)t));
        else        e = cosf(tt * expf(-0.2971077539347156f * (float)(t - 32)));
        emb_s[t] = e;
    }
    __syncthreads();
    {   // z1[t] = silu(emb . Wt1[:,t] + bt1[t])
        float acc = bt1[t];
        #pragma unroll 8
        for (int i = 0; i < 64; i++) acc += emb_s[i] * Wt1[i * 256 + t];
        z1_s[t] = acc / (1.f + expf(-acc));
    }
    __syncthreads();
    {   // out[j] = z1 . Wt2[:,j] + bt2[j], split over 4 partials
        int j = t & 63, p = t >> 6;
        float acc = 0.f;
        #pragma unroll 8
        for (int i = 0; i < 64; i++) acc += z1_s[p * 64 + i] * Wt2[(p * 64 + i) * 64 + j];
        ps_s[p][j] = acc;
    }
    __syncthreads();
    if (t < 64)
        table[tval * 64 + t] = ps_s[0][t] + ps_s[1][t] + ps_s[2][t] + ps_s[3][t] + bt2[t];
}

// ---- fused node kernel: h -> QKV -> Q, hidden, pre-scaled Kf0'(bf16), V(bf16) ----
__global__ __launch_bounds__(256) void k_node(
    const float* __restrict__ x, const int* __restrict__ time_steps,
    const float* __restrict__ temb, const float* __restrict__ Wi,
    const float* __restrict__ bi,
    const float* __restrict__ WQ, const float* __restrict__ bQ,
    const float* __restrict__ WK, const float* __restrict__ bK,
    const float* __restrict__ WV, const float* __restrict__ bV,
    const float* __restrict__ hopwise, const float* __restrict__ inv_deg,
    float* __restrict__ Q, unsigned short* __restrict__ Kf0,
    unsigned short* __restrict__ Vbuf, float* __restrict__ hidden, int n) {
    __shared__ float xs[16][128];                      // 8 KB
    __shared__ float hs[16][64];                       // 4 KB
    int j = threadIdx.x & 63;
    int slot = threadIdx.x >> 6;                       // wave id
    int nbase = blockIdx.x * 16;
    int nvalid = min(16, n - nbase);
    const float4* xg = (const float4*)(x + (size_t)nbase * 128);
    float4* xs4 = (float4*)&xs[0][0];
    for (int idx = threadIdx.x; idx < nvalid * 32; idx += 256) xs4[idx] = xg[idx];
    __syncthreads();
    int nl = slot * 4;
    {
        float acc[4];
        #pragma unroll
        for (int k = 0; k < 4; k++) acc[k] = 0.f;
        #pragma unroll 8
        for (int i = 0; i < 128; i++) {
            float w = Wi[i * 64 + j];
            #pragma unroll
            for (int k = 0; k < 4; k++) acc[k] += xs[nl + k][i] * w;
        }
        float bj = bi[j];
        #pragma unroll
        for (int k = 0; k < 4; k++) {
            int node = nbase + nl + k;
            float te = (node < n) ? temb[time_steps[node] * 64 + j] : 0.f;
            hs[nl + k][j] = fmaxf(acc[k] + bj + te, 0.f);
        }
    }
    __syncthreads();
    float aq[4], ak[4], av[4];
    #pragma unroll
    for (int k = 0; k < 4; k++) { aq[k] = bQ[j]; ak[k] = bK[j]; av[k] = bV[j]; }
    #pragma unroll 4
    for (int i = 0; i < 64; i++) {
        float wq = WQ[i * 64 + j], wk = WK[i * 64 + j], wv = WV[i * 64 + j];
        #pragma unroll
        for (int k = 0; k < 4; k++) {
            float hv = hs[nl + k][i];
            aq[k] += hv * wq; ak[k] += hv * wk; av[k] += hv * wv;
        }
    }
    float h0 = hopwise[0];
    #pragma unroll
    for (int k = 0; k < 4; k++) {
        int node = nbase + nl + k;
        if (node < n) {
            float q  = 1.f + ((aq[k] > 0.f) ? aq[k] : (expf(aq[k]) - 1.f));
            float kf = 1.f + ((ak[k] > 0.f) ? ak[k] : (expf(ak[k]) - 1.f));
            float inv = inv_deg[node];
            Q[(size_t)node * 64 + j] = q;
            Kf0[(size_t)node * 64 + j] = f2bf(kf * inv);       // pre-scaled Kf'
            Vbuf[(size_t)node * 64 + j] = f2bf(av[k]);
            hidden[(size_t)node * 64 + j] = av[k] * h0;
        }
    }
}

// ---- hop: wave-per-node (64 lanes), no LDS, no barriers; 2 nodes/block (128 thr).
// MODE 0: outer-product gather from Kf'(bf16) + V(bf16)  [hop 0]
// MODE 1: dense gather from M(fp8) rows                  [hops 1,2]
// Main loop: full DEPTH-groups; exact tail via wave-uniform guarded slots
// (degU uniform -> s_cbranch, no duplicate loads, loads still pipeline).
template<int MODE>
__global__ __launch_bounds__(128) void k_hop(
    const unsigned char* __restrict__ Mold, const unsigned short* __restrict__ Kfold,
    const unsigned short* __restrict__ Vbuf,
    const int* __restrict__ cnt, const int* __restrict__ csr,
    const float* __restrict__ inv_deg, const float* __restrict__ Q,
    const float* __restrict__ gamma,
    unsigned char* __restrict__ Mnew, unsigned short* __restrict__ Kfnew,
    float* __restrict__ hidden, int hop, int write_out,
    const float* __restrict__ Wo, const float* __restrict__ bo,
    const float* __restrict__ Wf1, float* __restrict__ out16,
    float* __restrict__ Pbuf, int n) {
    constexpr int DEPTH = (MODE == 0) ? 4 : 8;
    int lane = threadIdx.x & 63;
    int node = blockIdx.x * 2 + (threadIdx.x >> 6);
    if (node >= n) return;
    int grp = lane >> 4;                               // head h
    // prefetch everything independent up front
    int deg = min(cnt[node], SLOTS);
    int sidx = csr[(size_t)node * SLOTS + lane];       // all 64 slots, one load
    float qv = Q[(size_t)node * 64 + lane];
    size_t hoff = (size_t)node * 64 + lane;
    float hid_in = hidden[hoff];
    int degU = __builtin_amdgcn_readfirstlane(deg);
    float acc[16];
    #pragma unroll
    for (int t = 0; t < 16; t++) acc[t] = 0.f;
    float kacc = 0.f;

    int d = 0;
    for (; d + DEPTH <= degU; d += DEPTH) {
        unsigned short kraw[DEPTH];
        uint4 m0[DEPTH], m1[DEPTH];
        #pragma unroll
        for (int t = 0; t < DEPTH; t++) {
            int s = __builtin_amdgcn_readlane(sidx, d + t);   // SGPR base
            kraw[t] = Kfold[(size_t)s * 64 + lane];
            if constexpr (MODE == 0) {
                const uint4* vp = (const uint4*)((const unsigned char*)Vbuf + (size_t)s * 128 + grp * 32);
                m0[t] = vp[0]; m1[t] = vp[1];
            } else {
                m0[t] = *(const uint4*)(Mold + (size_t)s * MSZ + lane * 16);
            }
        }
        #pragma unroll
        for (int t = 0; t < DEPTH; t++) {
            float kf = bf2f(kraw[t]);
            kacc += kf;
            if constexpr (MODE == 0) {
                acc[0]  = fmaf(kf, bfu_lo(m0[t].x), acc[0]);
                acc[1]  = fmaf(kf, bfu_hi(m0[t].x), acc[1]);
                acc[2]  = fmaf(kf, bfu_lo(m0[t].y), acc[2]);
                acc[3]  = fmaf(kf, bfu_hi(m0[t].y), acc[3]);
                acc[4]  = fmaf(kf, bfu_lo(m0[t].z), acc[4]);
                acc[5]  = fmaf(kf, bfu_hi(m0[t].z), acc[5]);
                acc[6]  = fmaf(kf, bfu_lo(m0[t].w), acc[6]);
                acc[7]  = fmaf(kf, bfu_hi(m0[t].w), acc[7]);
                acc[8]  = fmaf(kf, bfu_lo(m1[t].x), acc[8]);
                acc[9]  = fmaf(kf, bfu_hi(m1[t].x), acc[9]);
                acc[10] = fmaf(kf, bfu_lo(m1[t].y), acc[10]);
                acc[11] = fmaf(kf, bfu_hi(m1[t].y), acc[11]);
                acc[12] = fmaf(kf, bfu_lo(m1[t].z), acc[12]);
                acc[13] = fmaf(kf, bfu_hi(m1[t].z), acc[13]);
                acc[14] = fmaf(kf, bfu_lo(m1[t].w), acc[14]);
                acc[15] = fmaf(kf, bfu_hi(m1[t].w), acc[15]);
            } else {
                f32x2 p;
                p = __builtin_amdgcn_cvt_pk_f32_fp8((int)m0[t].x, false); acc[0]  += p.x; acc[1]  += p.y;
                p = __builtin_amdgcn_cvt_pk_f32_fp8((int)m0[t].x, true);  acc[2]  += p.x; acc[3]  += p.y;
                p = __builtin_amdgcn_cvt_pk_f32_fp8((int)m0[t].y, false); acc[4]  += p.x; acc[5]  += p.y;
                p = __builtin_amdgcn_cvt_pk_f32_fp8((int)m0[t].y, true);  acc[6]  += p.x; acc[7]  += p.y;
                p = __builtin_amdgcn_cvt_pk_f32_fp8((int)m0[t].z, false); acc[8]  += p.x; acc[9]  += p.y;
                p = __builtin_amdgcn_cvt_pk_f32_fp8((int)m0[t].z, true);  acc[10] += p.x; acc[11] += p.y;
                p = __builtin_amdgcn_cvt_pk_f32_fp8((int)m0[t].w, false); acc[12] += p.x; acc[13] += p.y;
                p = __builtin_amdgcn_cvt_pk_f32_fp8((int)m0[t].w, true);  acc[14] += p.x; acc[15] += p.y;
            }
        }
    }
    // exact tail: slots guarded by wave-uniform branches (no dup loads)
    if (d < degU) {
        int rem = degU - d;                            // 1..DEPTH-1
        unsigned short kraw[DEPTH];
        uint4 m0[DEPTH], m1[DEPTH];
        #pragma unroll
        for (int t = 0; t < DEPTH - 1; t++) {
            if (t < rem) {
                int s = __builtin_amdgcn_readlane(sidx, d + t);
                kraw[t] = Kfold[(size_t)s * 64 + lane];
                if constexpr (MODE == 0) {
                    const uint4* vp = (const uint4*)((const unsigned char*)Vbuf + (size_t)s * 128 + grp * 32);
                    m0[t] = vp[0]; m1[t] = vp[1];
                } else {
                    m0[t] = *(const uint4*)(Mold + (size_t)s * MSZ + lane * 16);
                }
            }
        }
        #pragma unroll
        for (int t = 0; t < DEPTH - 1; t++) {
            if (t < rem) {
                float kf = bf2f(kraw[t]);
                kacc += kf;
                if constexpr (MODE == 0) {
                    acc[0]  = fmaf(kf, bfu_lo(m0[t].x), acc[0]);
                    acc[1]  = fmaf(kf, bfu_hi(m0[t].x), acc[1]);
                    acc[2]  = fmaf(kf, bfu_lo(m0[t].y), acc[2]);
                    acc[3]  = fmaf(kf, bfu_hi(m0[t].y), acc[3]);
                    acc[4]  = fmaf(kf, bfu_lo(m0[t].z), acc[4]);
                    acc[5]  = fmaf(kf, bfu_hi(m0[t].z), acc[5]);
                    acc[6]  = fmaf(kf, bfu_lo(m0[t].w), acc[6]);
                    acc[7]  = fmaf(kf, bfu_hi(m0[t].w), acc[7]);
                    acc[8]  = fmaf(kf, bfu_lo(m1[t].x), acc[8]);
                    acc[9]  = fmaf(kf, bfu_hi(m1[t].x), acc[9]);
                    acc[10] = fmaf(kf, bfu_lo(m1[t].y), acc[10]);
                    acc[11] = fmaf(kf, bfu_hi(m1[t].y), acc[11]);
                    acc[12] = fmaf(kf, bfu_lo(m1[t].z), acc[12]);
                    acc[13] = fmaf(kf, bfu_hi(m1[t].z), acc[13]);
                    acc[14] = fmaf(kf, bfu_lo(m1[t].w), acc[14]);
                    acc[15] = fmaf(kf, bfu_hi(m1[t].w), acc[15]);
                } else {
                    f32x2 p;
                    p = __builtin_amdgcn_cvt_pk_f32_fp8((int)m0[t].x, false); acc[0]  += p.x; acc[1]  += p.y;
                    p = __builtin_amdgcn_cvt_pk_f32_fp8((int)m0[t].x, true);  acc[2]  += p.x; acc[3]  += p.y;
                    p = __builtin_amdgcn_cvt_pk_f32_fp8((int)m0[t].y, false); acc[4]  += p.x; acc[5]  += p.y;
                    p = __builtin_amdgcn_cvt_pk_f32_fp8((int)m0[t].y, true);  acc[6]  += p.x; acc[7]  += p.y;
                    p = __builtin_amdgcn_cvt_pk_f32_fp8((int)m0[t].z, false); acc[8]  += p.x; acc[9]  += p.y;
                    p = __builtin_amdgcn_cvt_pk_f32_fp8((int)m0[t].z, true);  acc[10] += p.x; acc[11] += p.y;
                    p = __builtin_amdgcn_cvt_pk_f32_fp8((int)m0[t].w, false); acc[12] += p.x; acc[13] += p.y;
                    p = __builtin_amdgcn_cvt_pk_f32_fp8((int)m0[t].w, true);  acc[14] += p.x; acc[15] += p.y;
                }
            }
        }
    }

    if (write_out) {
        float inv = inv_deg[node];
        uint4 st;
        st.x = pack4fp8(acc[0] * inv,  acc[1] * inv,  acc[2] * inv,  acc[3] * inv);
        st.y = pack4fp8(acc[4] * inv,  acc[5] * inv,  acc[6] * inv,  acc[7] * inv);
        st.z = pack4fp8(acc[8] * inv,  acc[9] * inv,  acc[10] * inv, acc[11] * inv);
        st.w = pack4fp8(acc[12] * inv, acc[13] * inv, acc[14] * inv, acc[15] * inv);
        *(uint4*)(Mnew + (size_t)node * MSZ + lane * 16) = st;
        Kfnew[(size_t)node * 64 + lane] = f2bf(kacc * inv);
    }

    // C[h] = sum_i Q[h,i]*Kf[h,i]  — 16-lane allreduce within head group
    float c = qv * kacc;
    c += __shfl_xor(c, 1); c += __shfl_xor(c, 2); c += __shfl_xor(c, 4); c += __shfl_xor(c, 8);

    // H[h,j] = sum_i Q[h,i]*M[h,i,j] — reduce-scatter over the 16 i-lanes so
    // lane (h,i) ends holding H[h, j=i] (static indices only; no scratch).
    float w0[16];
    #pragma unroll
    for (int t = 0; t < 16; t++) w0[t] = qv * acc[t];
    float w1r[8];
    #pragma unroll
    for (int t = 0; t < 8; t++) {
        float a = w0[2 * t], b = w0[2 * t + 1];
        float mine = (lane & 1) ? b : a, th = (lane & 1) ? a : b;
        w1r[t] = mine + __shfl_xor(th, 1);
    }
    float w2r[4];
    #pragma unroll
    for (int t = 0; t < 4; t++) {
        float a = w1r[2 * t], b = w1r[2 * t + 1];
        float mine = (lane & 2) ? b : a, th = (lane & 2) ? a : b;
        w2r[t] = mine + __shfl_xor(th, 2);
    }
    float w3r[2];
    #pragma unroll
    for (int t = 0; t < 2; t++) {
        float a = w2r[2 * t], b = w2r[2 * t + 1];
        float mine = (lane & 4) ? b : a, th = (lane & 4) ? a : b;
        w3r[t] = mine + __shfl_xor(th, 4);
    }
    float Hv;
    {
        float a = w3r[0], b = w3r[1];
        float mine = (lane & 8) ? b : a, th = (lane & 8) ? a : b;
        Hv = mine + __shfl_xor(th, 8);
    }

    float g = gamma[hop * HEADS + grp];
    float contrib = g * Hv / (c + CST);
    if (write_out) {
        hidden[hoff] = hid_in + contrib;
    } else {
        // final hop: fused Wo projection + bo, plus per-node P1/P2 for edge head
        float hid = hid_in + contrib;
        const float4* wop = (const float4*)(Wo + lane * 16);
        float4 wo0 = wop[0], wo1 = wop[1], wo2 = wop[2], wo3 = wop[3];
        float v[16];
        v[0] = hid * wo0.x;  v[1] = hid * wo0.y;  v[2] = hid * wo0.z;  v[3] = hid * wo0.w;
        v[4] = hid * wo1.x;  v[5] = hid * wo1.y;  v[6] = hid * wo1.z;  v[7] = hid * wo1.w;
        v[8] = hid * wo2.x;  v[9] = hid * wo2.y;  v[10] = hid * wo2.z; v[11] = hid * wo2.w;
        v[12] = hid * wo3.x; v[13] = hid * wo3.y; v[14] = hid * wo3.z; v[15] = hid * wo3.w;
        #pragma unroll
        for (int m = 32; m >= 1; m >>= 1) {
            #pragma unroll
            for (int o = 0; o < 16; o++) v[o] += __shfl_xor(v[o], m);
        }
        #pragma unroll
        for (int o = 0; o < 16; o++) v[o] += bo[o];
        if (lane == 0) {
            float4* op = (float4*)(out16 + (size_t)node * 16);
            op[0] = make_float4(v[0],  v[1],  v[2],  v[3]);
            op[1] = make_float4(v[4],  v[5],  v[6],  v[7]);
            op[2] = make_float4(v[8],  v[9],  v[10], v[11]);
            op[3] = make_float4(v[12], v[13], v[14], v[15]);
        }
        if (lane < 32) {
            int o = lane & 15, half = lane >> 4;
            const float* wf = Wf1 + (size_t)(half * 16) * 16 + o;
            float p = 0.f;
            #pragma unroll
            for (int i = 0; i < 16; i++) p += v[i] * wf[i * 16];
            Pbuf[(size_t)node * 32 + lane] = p;         // [n][0:16]=P1(src), [16:32]=P2(dst)
        }
    }
}

// ---------------- edge regression head: z = P1[s] + P2[d] + b1 ----------------
__global__ __launch_bounds__(256) void k_edge(
    const int* __restrict__ src, const int* __restrict__ dst,
    const float* __restrict__ Pbuf,
    const float* __restrict__ bf1, const float* __restrict__ Wf2,
    const float* __restrict__ bf2,
    float* __restrict__ out, int fe) {
    __shared__ float b1[16];
    __shared__ float w2[16];
    __shared__ float b2s;
    int t = threadIdx.x;
    if (t < 16) { b1[t] = bf1[t]; w2[t] = Wf2[t]; }
    if (t == 0) b2s = bf2[0];
    __syncthreads();
    int e = blockIdx.x * 256 + t;
    if (e >= fe) return;
    int s = src[e], d = dst[e];
    const float4* p1 = (const float4*)(Pbuf + (size_t)s * 32);
    const float4* p2 = (const float4*)(Pbuf + (size_t)d * 32 + 16);
    float z[16];
    #pragma unroll
    for (int q = 0; q < 4; q++) {
        float4 a = p1[q]; float4 b = p2[q];
        z[q * 4 + 0] = a.x + b.x; z[q * 4 + 1] = a.y + b.y;
        z[q * 4 + 2] = a.z + b.z; z[q * 4 + 3] = a.w + b.w;
    }
    float acc = b2s;
    #pragma unroll
    for (int o = 0; o < 16; o++) {
        float zz = z[o] + b1[o];
        zz = zz / (1.f + expf(-zz));       // silu
        acc += zz * w2[o];
    }
    out[e] = acc;
}

extern "C" void kernel_launch(void* const* d_in, const int* in_sizes, int n_in,
                              void* d_out, int out_size, void* d_ws, size_t ws_size,
                              hipStream_t stream) {
    const float* x        = (const float*)d_in[0];
    const int*   eidx     = (const int*)d_in[1];
    const int*   feidx    = (const int*)d_in[2];
    const int*   tsteps   = (const int*)d_in[3];
    const float* Wi  = (const float*)d_in[4];
    const float* bi  = (const float*)d_in[5];
    const float* Wt1 = (const float*)d_in[6];
    const float* bt1 = (const float*)d_in[7];
    const float* Wt2 = (const float*)d_in[8];
    const float* bt2 = (const float*)d_in[9];
    const float* WQ  = (const float*)d_in[10];
    const float* bQ  = (const float*)d_in[11];
    const float* WK  = (const float*)d_in[12];
    const float* bK  = (const float*)d_in[13];
    const float* WV  = (const float*)d_in[14];
    const float* bV  = (const float*)d_in[15];
    const float* Wo  = (const float*)d_in[16];
    const float* bo  = (const float*)d_in[17];
    const float* hopwise  = (const float*)d_in[18];
    const float* headwise = (const float*)d_in[19];
    const float* Wf1 = (const float*)d_in[20];
    const float* bf1 = (const float*)d_in[21];
    const float* Wf2 = (const float*)d_in[22];
    const float* bf2 = (const float*)d_in[23];

    const int N  = in_sizes[3];
    const int E  = in_sizes[1] / 2;
    const int FE = in_sizes[2] / 2;
    const int* row = eidx;           // [0,:]
    const int* col = eidx + E;       // [1,:]
    const int* fsrc = feidx;
    const int* fdst = feidx + FE;

    // ---- workspace carve-up (256B aligned) ----
    char* ws = (char*)d_ws;
    size_t off = 0;
    auto alloc = [&](size_t bytes) -> char* {
        char* p = ws + off;
        off = (off + bytes + 255) & ~(size_t)255;
        return p;
    };
    float* gamma     = (float*)alloc(KHOP * HEADS * sizeof(float));
    int*   cnt       = (int*)alloc((size_t)N * 4);
    int*   csr       = (int*)alloc((size_t)N * SLOTS * 4);
    float* inv_deg   = (float*)alloc((size_t)N * 4);
    float* temb      = (float*)alloc((size_t)NUM_T * HC * 4);
    float* Qbuf      = (float*)alloc((size_t)N * HC * 4);
    unsigned short* Kf0  = (unsigned short*)alloc((size_t)N * HC * 2);
    unsigned short* Kf_a = (unsigned short*)alloc((size_t)N * HC * 2);
    unsigned short* Kf_b = (unsigned short*)alloc((size_t)N * HC * 2);
    unsigned short* Vbuf = (unsigned short*)alloc((size_t)N * HC * 2);
    float* hidden    = (float*)alloc((size_t)N * HC * 4);
    unsigned char* M_a = (unsigned char*)alloc((size_t)N * MSZ);
    unsigned char* M_b = (unsigned char*)alloc((size_t)N * MSZ);
    float* Pbuf      = (float*)alloc((size_t)N * 32 * 4);
    (void)ws_size;

    float* out_edges = (float*)d_out;            // [FE]
    float* out_hid16 = (float*)d_out + FE;       // [N,16]

    const int miscBlocks = NUM_T + (N + 255) / 256;
    const int hopBlocks = (N + 1) / 2;

    (void)hipMemsetAsync(cnt, 0, (size_t)N * 4, stream);
    k_fill<<<(E + 255) / 256, 256, 0, stream>>>(row, col, cnt, csr, E);
    k_misc<<<miscBlocks, 256, 0, stream>>>(Wt1, bt1, Wt2, bt2, hopwise, headwise,
                                           cnt, gamma, temb, inv_deg, N);
    k_node<<<(N + 15) / 16, 256, 0, stream>>>(x, tsteps, temb, Wi, bi,
                                              WQ, bQ, WK, bK, WV, bV, hopwise, inv_deg,
                                              Qbuf, Kf0, Vbuf, hidden, N);
    // hop 0: outer-product gather (Kf0', V) -> M_a', Kf_a'
    k_hop<0><<<hopBlocks, 128, 0, stream>>>(nullptr, Kf0, Vbuf, cnt, csr, inv_deg, Qbuf, gamma,
                                            M_a, Kf_a, hidden, 0, 1, Wo, bo, Wf1, out_hid16, Pbuf, N);
    // hop 1: dense M_a' -> M_b'
    k_hop<1><<<hopBlocks, 128, 0, stream>>>(M_a, Kf_a, nullptr, cnt, csr, inv_deg, Qbuf, gamma,
                                            M_b, Kf_b, hidden, 1, 1, Wo, bo, Wf1, out_hid16, Pbuf, N);
    // hop 2: dense gather M_b', no write, fused Wo projection + P1/P2
    k_hop<1><<<hopBlocks, 128, 0, stream>>>(M_b, Kf_b, nullptr, cnt, csr, inv_deg, Qbuf, gamma,
                                            M_a, Kf_a, hidden, 2, 0, Wo, bo, Wf1, out_hid16, Pbuf, N);
    k_edge<<<(FE + 255) / 256, 256, 0, stream>>>(fsrc, fdst, Pbuf, bf1, Wf2, bf2,
                                                 out_edges, FE);
}